// Round 9
// baseline (1088.203 us; speedup 1.0000x reference)
//
#include <hip/hip_runtime.h>
#include <math.h>

// Problem constants
#define DD 256            // latent dim
#define KK 8192           // codebook size
#define NN 16384          // rows
#define MT 16             // rows per block (2 row-groups x 8, K-split 2-way)
#define RPW 8             // rows per wave
#define NT 512            // cols per chunk (lane + 64*j, j 0..7)
#define NCHG 8            // chunks per col-group (16 total / 2 groups)
#define NBM (NN / MT)     // 1024 main blocks x 256 thr
#define NBLOCKS 512       // gather/partial grid (verified 32-row geometry)
#define RSTRIDE 260       // rowsumsq staging stride (unchanged, verified)
#define NPL 512           // planes per col-group stream (8 chunks x 64)

// Output layout (all float32, concatenated in reference return order)
#define OUT_IDS   0
#define OUT_Q     16384
#define OUT_ST    4210688          // 16384 + 4194304
#define OUT_COMMIT 8404992
#define OUT_CBL    8404993
#define OUT_PERP   8404994

// ---------------------------------------------------------------------------
// async global->LDS DMA: lane i's 16B lands at ldsbase + i*16 (contiguous 1KB).
// ---------------------------------------------------------------------------
__device__ __forceinline__ void gl2lds16(const float* g, float* l) {
    __builtin_amdgcn_global_load_lds(
        (const __attribute__((address_space(1))) float*)g,
        (__attribute__((address_space(3))) float*)l, 16, 0, 0);
}

// ---------------------------------------------------------------------------
// numpy pairwise-sum replica for sum of squares (verified bit-exact)
// ---------------------------------------------------------------------------
__device__ __forceinline__ float np_block128_sumsq(const float* p) {
    #pragma clang fp contract(off)
    float r0 = p[0] * p[0], r1 = p[1] * p[1], r2 = p[2] * p[2], r3 = p[3] * p[3];
    float r4 = p[4] * p[4], r5 = p[5] * p[5], r6 = p[6] * p[6], r7 = p[7] * p[7];
    for (int i = 8; i < 128; i += 8) {
        r0 = r0 + p[i + 0] * p[i + 0];
        r1 = r1 + p[i + 1] * p[i + 1];
        r2 = r2 + p[i + 2] * p[i + 2];
        r3 = r3 + p[i + 3] * p[i + 3];
        r4 = r4 + p[i + 4] * p[i + 4];
        r5 = r5 + p[i + 5] * p[i + 5];
        r6 = r6 + p[i + 6] * p[i + 6];
        r7 = r7 + p[i + 7] * p[i + 7];
    }
    return ((r0 + r1) + (r2 + r3)) + ((r4 + r5) + (r6 + r7));
}

__device__ __forceinline__ float np_pairwise256_sumsq(const float* a) {
    #pragma clang fp contract(off)
    float s0 = np_block128_sumsq(a);
    float s1 = np_block128_sumsq(a + 128);
    return s0 + s1;
}

// ---------------------------------------------------------------------------
// Kernel 1: per-row sum of squares, numpy-pairwise-exact (unchanged, verified)
// ---------------------------------------------------------------------------
__global__ __launch_bounds__(256) void rowsumsq(const float* __restrict__ A,
                                                float* __restrict__ out) {
    __shared__ __align__(16) float sA[64][RSTRIDE];
    const int tid = threadIdx.x;
    const int base = blockIdx.x * 64;
    #pragma unroll
    for (int i = 0; i < 16; ++i) {
        int g = i * 256 + tid;
        int row = g >> 6, d4 = g & 63;
        float4 v = reinterpret_cast<const float4*>(A)[(size_t)(base + row) * (DD / 4) + d4];
        *reinterpret_cast<float4*>(&sA[row][d4 * 4]) = v;
    }
    __syncthreads();
    if (tid < 64) out[base + tid] = np_pairwise256_sumsq(sA[tid]);
}

// ---------------------------------------------------------------------------
// Kernel 1b: codebook transpose into STREAM order (ROUND-9).
//   CBt2 float4 index (chg*64 + p)*512 + cw  =  CB[chg*512 + cw][4p .. 4p+3]
//   (chg = chunk 0..15, p = d4-plane 0..63, cw = col-in-chunk 0..511)
//   A col-group's walk (chunks ascending, planes ascending) is now one
//   LINEAR stream of 512 consecutive 8 KB planes -> DMA source is a single
//   running pointer. Bit-exact copy. Lives in out+OUT_Q scratch
//   (2,097,152 floats4... = 2M float4 = 8 MB); vq_gather overwrites it all.
// ---------------------------------------------------------------------------
__global__ __launch_bounds__(256) void cb_transpose2(const float* __restrict__ CB,
                                                     float4* __restrict__ CBt2) {
    const int id = blockIdx.x * 256 + threadIdx.x;   // 0 .. 2,097,151
    const int q  = id >> 9;           // chg*64 + p
    const int cw = id & 511;
    const int chg = q >> 6;
    const int p   = q & 63;
    const int col = chg * 512 + cw;
    CBt2[id] = *reinterpret_cast<const float4*>(CB + (size_t)col * DD + p * 4);
}

// ---------------------------------------------------------------------------
// Kernel 2: main VQ distance+argmin — ROUND-9: wave-private LDS stream with
//   COUNTED-vmcnt prefetch (T3/T4 pattern, barrier-free).
//   Evidence base: R6-R8 pin this kernel at 2 waves/SIMD; busy-time 677-691us
//   is already ~the m07-measured VALU ceiling (437us x 157/103 = 670us); the
//   recoverable term is ~230us of vmcnt stall. R8 proved the compiler
//   dismantles register double-buffers (VGPR 104 < needed 140) — so the
//   prefetch moves to LDS where it can't be undone:
//     - per wave: 2 x 8KB plane slots (ping-pong), wave-PRIVATE -> no
//       __syncthreads in the hot loop (the R0-R5 barrier poison can't return)
//     - plane q+2's 8 gl2lds DMAs issue BEFORE plane q's 256-fma block
//     - consume gate: inline-asm s_waitcnt vmcnt(8) (oldest plane drained,
//       next plane's 8 stay in flight; never 0 mid-loop) + sched_barrier
//       (rule #18); lgkmcnt(0) before reusing a slot for DMA
//   ds_read: contiguous b128 (lane*16 + j*1024) — conflict-free canonical.
//   X scalars, fma chain (d=0..255, x/y/z/w), score fl(fl(x2+c2)-2m),
//   first-index ties, butterfly argmin, strict-less cross-group merge:
//   ALL byte-identical to R7 (verified absmax 0.0). Only cc data routing
//   changed (global->LDS->reg instead of global->reg; same values).
//   NO launch_bounds arg2 (R0-R5 law: arg2 caps VGPR at 256/arg2).
// ---------------------------------------------------------------------------
__global__ __launch_bounds__(256) void vq_main(const float* __restrict__ X,
                                               const float4* __restrict__ CBt2,
                                               const float* __restrict__ c2,
                                               const float* __restrict__ x2,
                                               const float* __restrict__ mask,
                                               float* __restrict__ out,
                                               float* __restrict__ hist) {
    __shared__ __align__(16) float sCC[4 * 4096];   // 64 KB: 4 waves x 2 slots x 8KB
    __shared__ float gbest[2][MT];
    __shared__ int   gidx[2][MT];

    const int tid  = threadIdx.x;
    const int lane = tid & 63;
    const int wid  = tid >> 6;                                  // 0..3
    const int widu = __builtin_amdgcn_readfirstlane(wid);       // uniform copy
    const int g    = wid >> 1;        // col-group (0: cols 0..4095, 1: 4096..8191)
    const int gu   = widu >> 1;
    const int wg   = wid & 1;         // row-group (8 rows each)
    const int wgu  = widu & 1;
    const int block_row = blockIdx.x * MT;

    // wave-private LDS slot pointers
    float* const dl0 = &sCC[widu * 4096];          // DMA dst, slot 0 (uniform)
    float* const dl1 = dl0 + 2048;                 // DMA dst, slot 1
    const float* const sl0 = dl0 + lane * 4;       // read base, slot 0
    const float* const sl1 = sl0 + 2048;           // read base, slot 1

    // uniform X row base -> scalar loads in the hot loop (R7-verified path)
    const float* xr = X + (size_t)(block_row + wgu * RPW) * DD;

    // row constants (bit-identical to numpy's x2)
    float x2r[RPW];
    #pragma unroll
    for (int rr = 0; rr < RPW; ++rr) x2r[rr] = x2[block_row + wg * RPW + rr];

    float best[RPW];
    int   besti[RPW];
    #pragma unroll
    for (int rr = 0; rr < RPW; ++rr) { best[rr] = 3.4e38f; besti[rr] = 0; }

    // DMA source stream: group gu's planes are CBt2[gu*512*512 ...], linear.
    const float4* srcq = CBt2 + (size_t)gu * NPL * 512 + lane;

    // prologue: planes 0 and 1 in flight (16 outstanding)
    #pragma unroll
    for (int k = 0; k < 8; ++k) gl2lds16((const float*)(srcq + k * 64), dl0 + k * 256);
    srcq += 512;
    #pragma unroll
    for (int k = 0; k < 8; ++k) gl2lds16((const float*)(srcq + k * 64), dl1 + k * 256);
    srcq += 512;

    for (int ch = 0; ch < NCHG; ++ch) {
        const int chg = gu * NCHG + ch;       // global chunk id (uniform)
        float c2v[8];
        #pragma unroll
        for (int j = 0; j < 8; ++j) c2v[j] = c2[chg * NT + lane + 64 * j];

        float acc[8][8];
        #pragma unroll
        for (int rr = 0; rr < 8; ++rr)
            #pragma unroll
            for (int j = 0; j < 8; ++j) acc[rr][j] = 0.0f;

        #pragma unroll 2
        for (int p = 0; p < 64; ++p) {
            const int q = ch * 64 + p;        // global plane 0..511 (uniform)

            // gate on plane q's 8 DMAs (oldest); q+1's 8 stay in flight
            if (q == NPL - 1) { asm volatile("s_waitcnt vmcnt(0)" ::: "memory"); }
            else              { asm volatile("s_waitcnt vmcnt(8)" ::: "memory"); }
            __builtin_amdgcn_sched_barrier(0);

            // plane q -> registers (contiguous b128, conflict-free)
            const float* sb = (q & 1) ? sl1 : sl0;
            float4 cc[8];
            #pragma unroll
            for (int j = 0; j < 8; ++j)
                cc[j] = *reinterpret_cast<const float4*>(sb + j * 256);
            asm volatile("s_waitcnt lgkmcnt(0)" ::: "memory");   // reads landed
            __builtin_amdgcn_sched_barrier(0);

            // issue plane q+2 into the slot just freed (same parity)
            if (q < NPL - 2) {
                float* db = (q & 1) ? dl1 : dl0;
                #pragma unroll
                for (int k = 0; k < 8; ++k)
                    gl2lds16((const float*)(srcq + k * 64), db + k * 256);
                srcq += 512;
            }

            // ---- 256-fma block: chain d=0..255 in x/y/z/w order (bit-exact) ----
            #pragma unroll
            for (int rr = 0; rr < 8; ++rr) {
                const float sx = xr[rr * DD + p * 4 + 0];
                const float sy = xr[rr * DD + p * 4 + 1];
                const float sz = xr[rr * DD + p * 4 + 2];
                const float sw = xr[rr * DD + p * 4 + 3];
                #pragma unroll
                for (int j = 0; j < 8; ++j) {
                    acc[rr][j] = fmaf(sx, cc[j].x, acc[rr][j]);
                    acc[rr][j] = fmaf(sy, cc[j].y, acc[rr][j]);
                    acc[rr][j] = fmaf(sz, cc[j].z, acc[rr][j]);
                    acc[rr][j] = fmaf(sw, cc[j].w, acc[rr][j]);
                }
            }
        }

        // ---- fp32 distance exactly as numpy, then argmin (first-index ties) ----
        #pragma unroll
        for (int rr = 0; rr < 8; ++rr) {
            #pragma unroll
            for (int j = 0; j < 8; ++j) {
                const int col = chg * NT + lane + 64 * j;
                float t1 = x2r[rr] + c2v[j];
                float sc = t1 - 2.0f * acc[rr][j];
                if (sc < best[rr] || (sc == best[rr] && col < besti[rr])) {
                    best[rr] = sc; besti[rr] = col;
                }
            }
        }
    }

    // ---- per-row argmin across the wave's 64 lanes (xor butterfly) ----
    #pragma unroll
    for (int rr = 0; rr < RPW; ++rr) {
        float b = best[rr];
        int  bi = besti[rr];
        #pragma unroll
        for (int m = 32; m > 0; m >>= 1) {
            float b2 = __shfl_xor(b, m, 64);
            int   i2 = __shfl_xor(bi, m, 64);
            if (b2 < b || (b2 == b && i2 < bi)) { b = b2; bi = i2; }
        }
        if (lane == 0) {
            gbest[g][wg * RPW + rr] = b;
            gidx [g][wg * RPW + rr] = bi;
        }
    }
    __syncthreads();   // the only block-wide barrier

    // ---- cross-group merge: group 0 has lower cols, so tie -> group 0 ----
    if (tid < MT) {
        const float b0 = gbest[0][tid], b1 = gbest[1][tid];
        const int bi = (b1 < b0) ? gidx[1][tid] : gidx[0][tid];
        out[OUT_IDS + block_row + tid] = (float)bi;   // exact integer in float
        atomicAdd(&hist[bi], mask[block_row + tid]);  // mask=1.0 -> order-exact
    }
}

// ---------------------------------------------------------------------------
// Kernel 2b: gather + MSE partials. 512 blocks x 256 threads, VERBATIM the
//   verified R0 epilogue -> partial[512] and outq/outst bit-identical.
//   Overwrites the CBt2 scratch region entirely.
// ---------------------------------------------------------------------------
__global__ __launch_bounds__(256) void vq_gather(const float* __restrict__ X,
                                                 const float* __restrict__ CB,
                                                 float* __restrict__ out,
                                                 float* __restrict__ partial) {
    __shared__ int   row_id[32];
    __shared__ float wsum[4];
    const int tid  = threadIdx.x;
    const int lane = tid & 63;
    const int wid  = tid >> 6;
    const int block_row = blockIdx.x * 32;

    if (tid < 32) row_id[tid] = (int)out[OUT_IDS + block_row + tid];
    __syncthreads();

    float msep = 0.0f;
    float* outq  = out + OUT_Q;
    float* outst = out + OUT_ST;
    #pragma unroll
    for (int i = 0; i < 8; ++i) {
        int g2 = i * 256 + tid;         // 0..2047 covers 32 rows x 64 float4
        int row = g2 >> 6;
        int d4  = g2 & 63;
        int id  = row_id[row];
        float4 q = reinterpret_cast<const float4*>(CB)[(size_t)id * (DD / 4) + d4];
        float4 x = reinterpret_cast<const float4*>(X)[(size_t)(block_row + row) * (DD / 4) + d4];
        float4 st;
        st.x = x.x + (q.x - x.x);
        st.y = x.y + (q.y - x.y);
        st.z = x.z + (q.z - x.z);
        st.w = x.w + (q.w - x.w);
        float dx = x.x - q.x; msep = fmaf(dx, dx, msep);
        dx = x.y - q.y; msep = fmaf(dx, dx, msep);
        dx = x.z - q.z; msep = fmaf(dx, dx, msep);
        dx = x.w - q.w; msep = fmaf(dx, dx, msep);
        size_t o = (size_t)(block_row + row) * (DD / 4) + d4;
        reinterpret_cast<float4*>(outq)[o]  = q;
        reinterpret_cast<float4*>(outst)[o] = st;
    }
    #pragma unroll
    for (int off = 32; off > 0; off >>= 1) msep += __shfl_down(msep, off, 64);
    if (lane == 0) wsum[wid] = msep;
    __syncthreads();
    if (tid == 0) partial[blockIdx.x] = wsum[0] + wsum[1] + wsum[2] + wsum[3];
}

// ---------------------------------------------------------------------------
// Kernel 3: finalize losses + perplexity (double precision, single block)
// ---------------------------------------------------------------------------
__global__ __launch_bounds__(256) void vq_finalize(const float* __restrict__ partial,
                                                   const float* __restrict__ hist,
                                                   float* __restrict__ out) {
    __shared__ double red[256];
    const int tid = threadIdx.x;

    double ps = 0.0;
    for (int j = tid; j < NBLOCKS; j += 256) ps += (double)partial[j];
    red[tid] = ps;
    __syncthreads();
    for (int s = 128; s > 0; s >>= 1) {
        if (tid < s) red[tid] += red[tid + s];
        __syncthreads();
    }
    double mse_sum = red[0];
    __syncthreads();

    double hs = 0.0;
    for (int j = tid; j < KK; j += 256) hs += (double)hist[j];
    red[tid] = hs;
    __syncthreads();
    for (int s = 128; s > 0; s >>= 1) {
        if (tid < s) red[tid] += red[tid + s];
        __syncthreads();
    }
    double denom = red[0] > 1.0 ? red[0] : 1.0;
    __syncthreads();

    double ent = 0.0;
    for (int j = tid; j < KK; j += 256) {
        double p = (double)hist[j] / denom;
        ent += p * log(p + 1e-8);
    }
    red[tid] = ent;
    __syncthreads();
    for (int s = 128; s > 0; s >>= 1) {
        if (tid < s) red[tid] += red[tid + s];
        __syncthreads();
    }

    if (tid == 0) {
        double mse = mse_sum / (double)((size_t)NN * DD);
        out[OUT_COMMIT] = (float)(mse * 0.25);
        out[OUT_CBL]    = (float)mse;
        out[OUT_PERP]   = (float)exp(-red[0]);
    }
}

// ---------------------------------------------------------------------------
extern "C" void kernel_launch(void* const* d_in, const int* in_sizes, int n_in,
                              void* d_out, int out_size, void* d_ws, size_t ws_size,
                              hipStream_t stream) {
    const float* latents = (const float*)d_in[0];   // [16,1024,256]
    const float* mask    = (const float*)d_in[1];   // [16,1024]
    const float* cb      = (const float*)d_in[2];   // [8192,256]
    float* out = (float*)d_out;

    // workspace layout (floats): hist[8192] | partial[512] | c2[8192] | x2[16384]
    float* hist    = (float*)d_ws;
    float* partial = hist + KK;
    float* c2      = partial + NBLOCKS;
    float* x2      = c2 + KK;

    // stream-ordered codebook scratch in the out buffer's OUT_Q region
    // (2M float4 = 8 MB <= region); vq_gather later overwrites all of it.
    float4* cbt2 = reinterpret_cast<float4*>(out + OUT_Q);

    hipMemsetAsync(d_ws, 0, KK * sizeof(float), stream);    // zero histogram
    rowsumsq<<<KK / 64, 256, 0, stream>>>(cb, c2);           // numpy-exact |c|^2
    rowsumsq<<<NN / 64, 256, 0, stream>>>(latents, x2);      // numpy-exact |x|^2
    cb_transpose2<<<(64 * KK) / 256, 256, 0, stream>>>(cb, cbt2);
    vq_main<<<NBM, 256, 0, stream>>>(latents, cbt2, c2, x2, mask, out, hist);
    vq_gather<<<NBLOCKS, 256, 0, stream>>>(latents, cb, out, partial);
    vq_finalize<<<1, 256, 0, stream>>>(partial, hist, out);
}